// Round 9
// baseline (392.109 us; speedup 1.0000x reference)
//
#include <hip/hip_runtime.h>
#include <hip/hip_bf16.h>
#include <math.h>

#define Bb   64
#define Nn   256
#define Mm   16
#define ONF  92
#define OEF  41
#define NF   128
#define EF   64
#define KDIM 320   // 2*NF + EF
#define ODIM 256   // 2*NF
#define FINAL 128
#define K0C  6     // conv K-chunks (K=192: gather 128 + edge 64)
#define NNODES (Bb * Nn)   // 16384

#define LOG2E_F 1.44269504088896f
#define LN2_F   0.6931471805599453f

typedef __attribute__((ext_vector_type(8))) short short8;
typedef __attribute__((ext_vector_type(4))) float f32x4;

#define AS1 __attribute__((address_space(1)))
#define AS3 __attribute__((address_space(3)))

// async global->LDS DMA, 16B per lane. LDS dest = wave-uniform base + lane*16;
// global source is per-lane. Drained by the vmcnt(0) implicit in __syncthreads().
__device__ __forceinline__ void gl2lds16(const void* gp, void* lp) {
    __builtin_amdgcn_global_load_lds((AS1 void*)(void*)gp, (AS3 void*)lp, 16, 0, 0);
}

__device__ __forceinline__ float sigmoidf_(float x) {
    float e = __expf(-x);
    return __builtin_amdgcn_rcpf(1.0f + e);
}
__device__ __forceinline__ float softplusf_(float x) {
    return fmaxf(x, 0.0f) + __logf(1.0f + __expf(-fabsf(x)));
}
__device__ __forceinline__ __hip_bfloat16 to_bf16(float x) { return __float2bfloat16(x); }

// ---------- mega-prep: all weight swizzles + WeT + DA in ONE launch ----------
__device__ __forceinline__ void swz(const float* __restrict__ in, __hip_bfloat16* __restrict__ out,
                                    int t, int Itot, int koff, int Kuse, int K0, float scale)
{
    int j = t & 7;
    int u = t >> 3;
    int lane = u & 63;
    int ln16 = lane & 15, q = lane >> 4;
    int v = u >> 6;
    int k0 = v % K0, tile = v / K0;
    int n = tile * 16 + ln16, k = k0 * 32 + q * 8 + j;
    out[t] = (k < Kuse) ? to_bf16(scale * in[(size_t)n * Itot + koff + k]) : to_bf16(0.0f);
}

#define SZ_WET (OEF * EF)          // 2624
#define SZ_WB  (16 * K0C * 512)    // 49152
#define SZ_WS  (16 * 4 * 512)      // 32768
#define SZ_WNB ((NF / 16) * 3 * 512)
#define SZ_WEB ((EF / 16) * 2 * 512)
#define SZ_WFB ((64 / 16) * 4 * 512)
#define SZ_DA  (Nn * Nn)
#define PREP_TOTAL (SZ_WET + 3 * SZ_WB + 3 * SZ_WS + SZ_WNB + SZ_WEB + SZ_WFB + SZ_DA)

__global__ __launch_bounds__(256) void k_prep(
    const float* __restrict__ We, const float* __restrict__ W1,
    const float* __restrict__ W2, const float* __restrict__ W3,
    const float* __restrict__ Wn, const float* __restrict__ Wf,
    const float* __restrict__ dis, const float* __restrict__ pw, const float* __restrict__ pb,
    float* __restrict__ WeT,
    __hip_bfloat16* __restrict__ W1b, __hip_bfloat16* __restrict__ W2b, __hip_bfloat16* __restrict__ W3b,
    __hip_bfloat16* __restrict__ W1s, __hip_bfloat16* __restrict__ W2s, __hip_bfloat16* __restrict__ W3s,
    __hip_bfloat16* __restrict__ Wnb, __hip_bfloat16* __restrict__ Web, __hip_bfloat16* __restrict__ Wfb,
    __hip_bfloat16* __restrict__ DAf)
{
    int t = blockIdx.x * 256 + threadIdx.x;
    if (t < SZ_WET) {
        int o = t / OEF, i = t - o * OEF;
        WeT[i * EF + o] = We[t];
        return;
    }
    t -= SZ_WET;
    if (t < SZ_WB) { swz(W1, W1b, t, KDIM, NF, 192, K0C, LOG2E_F); return; }
    t -= SZ_WB;
    if (t < SZ_WB) { swz(W2, W2b, t, KDIM, NF, 192, K0C, LOG2E_F); return; }
    t -= SZ_WB;
    if (t < SZ_WB) { swz(W3, W3b, t, KDIM, NF, 192, K0C, LOG2E_F); return; }
    t -= SZ_WB;
    if (t < SZ_WS) { swz(W1, W1s, t, KDIM, 0, NF, 4, LOG2E_F); return; }
    t -= SZ_WS;
    if (t < SZ_WS) { swz(W2, W2s, t, KDIM, 0, NF, 4, LOG2E_F); return; }
    t -= SZ_WS;
    if (t < SZ_WS) { swz(W3, W3s, t, KDIM, 0, NF, 4, LOG2E_F); return; }
    t -= SZ_WS;
    if (t < SZ_WNB) { swz(Wn, Wnb, t, ONF, 0, ONF, 3, 1.0f); return; }
    t -= SZ_WNB;
    if (t < SZ_WEB) { swz(We, Web, t, OEF, 0, OEF, 2, 1.0f); return; }
    t -= SZ_WEB;
    if (t < SZ_WFB) { swz(Wf, Wfb, t, NF, 0, NF, 4, 1.0f); return; }
    t -= SZ_WFB;
    if (t < SZ_DA) {
        int i = t >> 8, jx = t & 255;
        float v = sigmoidf_(fmaf(*pw, dis[t], *pb));
        int itile = i >> 4, ln16 = i & 15;
        int k0 = jx >> 5, q = (jx >> 3) & 3, jj = jx & 7;
        DAf[(size_t)((((itile * 8 + k0) << 6) + (q << 4) + ln16)) * 8 + jj] = to_bf16(v);
    }
}

// ---------- generic MFMA embed body ----------
template<int KIN, int K0, int NCOLS>
__device__ __forceinline__ void emb_body(
    int bid, const float* __restrict__ X, const __hip_bfloat16* __restrict__ Bswz,
    const float* __restrict__ bias, __hip_bfloat16* __restrict__ Y,
    __hip_bfloat16* A_s, __hip_bfloat16* O_s)
{
    constexpr int KP = K0 * 32;
    constexpr int TPW = NCOLS / 64;
    constexpr int OLD = NCOLS + 24;

    const int row0 = bid * 64;
    const int t = threadIdx.x;

    {
        const float4* Xb = (const float4*)(X + (size_t)row0 * KIN);
        constexpr int NV = (64 * KIN) / 4;
        for (int c = t; c < NV; c += 256) {
            float4 v = Xb[c];
            int flat = c * 4;
            #pragma unroll
            for (int e = 0; e < 4; e++) {
                int f = flat + e;
                int row = f / KIN, k = f - row * KIN;
                int mt = row >> 4, ln16 = row & 15;
                int k0 = k >> 5, q = (k >> 3) & 3, j = k & 7;
                float vv = (e == 0) ? v.x : (e == 1) ? v.y : (e == 2) ? v.z : v.w;
                A_s[(((mt * K0 + k0) << 6) + (q << 4) + ln16) * 8 + j] = to_bf16(vv);
            }
        }
        constexpr int PAD = KP - KIN;
        for (int c = t; c < 64 * PAD; c += 256) {
            int row = c / PAD, k = KIN + (c - row * PAD);
            int mt = row >> 4, ln16 = row & 15;
            int k0 = k >> 5, q = (k >> 3) & 3, j = k & 7;
            A_s[(((mt * K0 + k0) << 6) + (q << 4) + ln16) * 8 + j] = to_bf16(0.0f);
        }
    }
    __syncthreads();

    const int wv = t >> 6, lane = t & 63;
    const int q = lane >> 4, ln16 = lane & 15;

    f32x4 acc[4][TPW];
    #pragma unroll
    for (int p = 0; p < TPW; p++) {
        float bv = bias[(wv * TPW + p) * 16 + ln16];
        #pragma unroll
        for (int mt = 0; mt < 4; mt++) acc[mt][p] = (f32x4){bv, bv, bv, bv};
    }

    short8 bw[TPW][K0];
    #pragma unroll
    for (int p = 0; p < TPW; p++)
        #pragma unroll
        for (int k0 = 0; k0 < K0; k0++)
            bw[p][k0] = *(const short8*)(Bswz + ((size_t)((wv * TPW + p) * K0 + k0) << 9) + (lane << 3));

    #pragma unroll
    for (int k0 = 0; k0 < K0; k0++) {
        short8 af[4];
        #pragma unroll
        for (int mt = 0; mt < 4; mt++)
            af[mt] = *(const short8*)(A_s + (((mt * K0 + k0) << 6) + lane) * 8);
        #pragma unroll
        for (int mt = 0; mt < 4; mt++)
            #pragma unroll
            for (int p = 0; p < TPW; p++)
                acc[mt][p] = __builtin_amdgcn_mfma_f32_16x16x32_bf16(af[mt], bw[p][k0], acc[mt][p], 0, 0, 0);
    }

    #pragma unroll
    for (int mt = 0; mt < 4; mt++)
        #pragma unroll
        for (int p = 0; p < TPW; p++) {
            int col = (wv * TPW + p) * 16 + ln16;
            #pragma unroll
            for (int r = 0; r < 4; r++)
                O_s[(mt * 16 + q * 4 + r) * OLD + col] = to_bf16(acc[mt][p][r]);
        }
    __syncthreads();
    constexpr int CH = NCOLS / 8;
    for (int c = t; c < 64 * CH; c += 256) {
        int row = c / CH, ch = c - row * CH;
        *(uint4*)(Y + (size_t)(row0 + row) * NCOLS + ch * 8) =
            *(const uint4*)(O_s + row * OLD + ch * 8);
    }
}

// blocks [0,256): node embed; [256, 256+4096): edge embed
__global__ __launch_bounds__(256) void k_embed_all(
    const float* __restrict__ node_fea, const __hip_bfloat16* __restrict__ Wnb,
    const float* __restrict__ bn, __hip_bfloat16* __restrict__ nf0,
    const float* __restrict__ edge_fea, const __hip_bfloat16* __restrict__ Web,
    const float* __restrict__ be, __hip_bfloat16* __restrict__ efb)
{
    __shared__ __align__(16) __hip_bfloat16 A_s[4 * 3 * 512];
    __shared__ __align__(16) __hip_bfloat16 O_s[64 * (NF + 24)];
    if (blockIdx.x < 256)
        emb_body<ONF, 3, NF>(blockIdx.x, node_fea, Wnb, bn, nf0, A_s, O_s);
    else
        emb_body<OEF, 2, EF>(blockIdx.x - 256, edge_fea, Web, be, efb, A_s, O_s);
}

// ---------- S GEMM: S[n][o] = log2e*(nf[n] @ Wself[o] + bias[o]), f32 out ----------
// QIN=false: nf is standard [node][128]. QIN=true: quartered [4][NNODES][32].
template<bool QIN>
__global__ __launch_bounds__(256) void k_gemm_s(
    const __hip_bfloat16* __restrict__ nf,
    const __hip_bfloat16* __restrict__ Ws,
    const float* __restrict__ bias,
    float* __restrict__ S)
{
    __shared__ __align__(16) __hip_bfloat16 A_s[16 * 512];
    const int row0 = blockIdx.x * 64;
    const int t = threadIdx.x;
    const int wv = t >> 6, lane = t & 63;
    const int q = lane >> 4, ln16 = lane & 15;

    #pragma unroll
    for (int k0 = 0; k0 < 4; k0++) {
        const int node = row0 + (wv << 4) + ln16;
        const __hip_bfloat16* src = QIN
            ? nf + ((size_t)k0 * NNODES + node) * 32 + q * 8
            : nf + (size_t)node * NF + k0 * 32 + q * 8;
        gl2lds16(src, A_s + ((wv * 4 + k0) * 64 + lane) * 8);
    }
    __syncthreads();

    short8 bw[4][4];
    #pragma unroll
    for (int p = 0; p < 4; p++)
        #pragma unroll
        for (int k0 = 0; k0 < 4; k0++)
            bw[p][k0] = *(const short8*)(Ws + ((size_t)((wv * 4 + p) * 4 + k0) << 9) + (lane << 3));

    f32x4 acc[4][4];
    #pragma unroll
    for (int p = 0; p < 4; p++) {
        float bv = bias[(wv * 4 + p) * 16 + ln16] * LOG2E_F;
        #pragma unroll
        for (int mt = 0; mt < 4; mt++) acc[mt][p] = (f32x4){bv, bv, bv, bv};
    }

    #pragma unroll
    for (int k0 = 0; k0 < 4; k0++) {
        short8 af[4];
        #pragma unroll
        for (int mt = 0; mt < 4; mt++)
            af[mt] = *(const short8*)(A_s + ((mt * 4 + k0) * 64 + lane) * 8);
        #pragma unroll
        for (int mt = 0; mt < 4; mt++)
            #pragma unroll
            for (int p = 0; p < 4; p++)
                acc[mt][p] = __builtin_amdgcn_mfma_f32_16x16x32_bf16(af[mt], bw[p][k0], acc[mt][p], 0, 0, 0);
    }

    #pragma unroll
    for (int mt = 0; mt < 4; mt++)
        #pragma unroll
        for (int p = 0; p < 4; p++) {
            int col = (wv * 4 + p) * 16 + ln16;
            #pragma unroll
            for (int r = 0; r < 4; r++)
                S[(size_t)(row0 + mt * 16 + q * 4 + r) * ODIM + col] = acc[mt][p][r];
        }
}

// ---------- conv layer R9: quarter colsets + quartered OUTPUT layout ----------
// R8 residual problem: nf_out standard layout -> each quarter-block wrote 64B of
// a 256B node row; 128B lines assembled from stores of DIFFERENT blocks ->
// partial-dirty evictions + RMW = 117MB HBM writes for 4MB of stores.
// R9: output is quartered [4][NNODES][32] bf16. Each wave writes its group's
// 4 nodes x 64B CONTIGUOUSLY (256B region, full 128B lines completed by one
// wave within one epilogue pass) -> clean full-line writes, zero RMW.
// Readers retargeted: gather chunk k0 = quarter k0 (16B/lane contiguous),
// self-read = quarter qs. QIN selects input layout (layer1 reads standard
// embed output; layers 2-3 read quartered). Math bit-identical to R8.
template<bool QIN>
__global__ __launch_bounds__(256, 5) void k_conv_q(
    const __hip_bfloat16* __restrict__ nf_in,   // std [node][128] or quartered
    const __hip_bfloat16* __restrict__ ef_bf,   // [B*N*M][EF] bf16
    const int*   __restrict__ eidx,             // [B*N][16]
    const __hip_bfloat16* __restrict__ Wb,      // [16][K0C][512] (log2e*W[:,128:320])
    const float* __restrict__ Sbuf,             // [B*N][ODIM] f32 = log2e*(self+bias)
    const float* __restrict__ palpha,
    __hip_bfloat16* __restrict__ nf_out)        // quartered [4][NNODES][32] bf16
{
    __shared__ __align__(16) __hip_bfloat16 Wl[4 * K0C * 512];   // 24576 B

    const int t = threadIdx.x;
    const int wv = t >> 6, lane = t & 63;
    const int q = lane >> 4, ln16 = lane & 15;
    const int qs = (blockIdx.x >> 3) & 3;        // column quarter (XCD-safe bits)
    const int gb = ((blockIdx.x >> 5) << 3) | (blockIdx.x & 7);  // group octet 0..511
    const float alpha = *palpha;

    // ---- stage 4 weight tiles (1536 chunks of 16B; 6 per thread; dest linear)
    #pragma unroll
    for (int p = 0; p < 6; p++) {
        int idx = p * 256 + t;
        int tll = idx / 384;                     // local tile 0..3 (384 chunks each)
        int cin = idx - tll * 384;
        int gt = (tll < 2) ? (2 * qs + tll) : (8 + 2 * qs + (tll - 2));
        gl2lds16(Wb + (size_t)gt * (K0C * 512) + cin * 8, Wl + (size_t)idx * 8);
    }
    __syncthreads();   // the ONLY barrier; waves free-run below

    #pragma unroll 1
    for (int task = 0; task < 2; task++) {
        const int g = gb * 8 + (task << 2) + wv;      // group of 4 nodes
        const int node0g = g * 4;
        const int bbase = node0g & ~255;
        const int jv = eidx[(node0g << 4) + lane];    // lane = edge slot in group
        const unsigned long long mball = __ballot(jv >= 0);

        #pragma unroll 1
        for (int h = 0; h < 2; h++) {
            // ---- A-fragments for nodes 2h, 2h+1 direct from global (48 VGPR)
            short8 afr[2][K0C];
            float sF[2][2], sC[2][2], svv[2][2];
            #pragma unroll
            for (int mtl = 0; mtl < 2; mtl++) {
                const int mt = 2 * h + mtl;
                int jm = __shfl(jv, (mt << 4) + ln16);
                jm = jm < 0 ? 0 : jm;
                #pragma unroll
                for (int k0 = 0; k0 < 4; k0++) {
                    const __hip_bfloat16* gp = QIN
                        ? nf_in + ((size_t)k0 * NNODES + (bbase + jm)) * 32 + q * 8
                        : nf_in + (size_t)(bbase + jm) * NF + k0 * 32 + q * 8;
                    afr[mtl][k0] = *(const short8*)gp;
                }
                const __hip_bfloat16* ep =
                    ef_bf + ((size_t)((node0g + mt) << 4) + ln16) * EF + q * 8;
                afr[mtl][4] = *(const short8*)(ep);
                afr[mtl][5] = *(const short8*)(ep + 32);

                const int gnode = node0g + mt;
                const float* Sr = Sbuf + (size_t)gnode * ODIM + qs * 32 + ln16;
                const __hip_bfloat16* nr = QIN
                    ? nf_in + ((size_t)qs * NNODES + gnode) * 32 + ln16
                    : nf_in + (size_t)gnode * NF + qs * 32 + ln16;
                #pragma unroll
                for (int c = 0; c < 2; c++) {
                    sF[mtl][c] = Sr[c * 16];
                    sC[mtl][c] = Sr[128 + c * 16];
                    svv[mtl][c] = __bfloat162float(nr[c * 16]);
                }
            }

            // ---- per col-tile: K-loop (LDS weights) + fused epilogue
            #pragma unroll 1
            for (int ctl = 0; ctl < 2; ctl++) {
                f32x4 accF[2], accC[2];
                #pragma unroll
                for (int mtl = 0; mtl < 2; mtl++) {
                    float vF = sF[mtl][ctl], vC = sC[mtl][ctl];
                    accF[mtl] = (f32x4){vF, vF, vF, vF};
                    accC[mtl] = (f32x4){vC, vC, vC, vC};
                }
                #pragma unroll
                for (int k0 = 0; k0 < K0C; k0++) {
                    short8 wF = *(const short8*)(Wl + (((ctl)     * K0C + k0) << 9) + (lane << 3));
                    short8 wC = *(const short8*)(Wl + (((2 + ctl) * K0C + k0) << 9) + (lane << 3));
                    #pragma unroll
                    for (int mtl = 0; mtl < 2; mtl++) {
                        accF[mtl] = __builtin_amdgcn_mfma_f32_16x16x32_bf16(afr[mtl][k0], wF, accF[mtl], 0, 0, 0);
                        accC[mtl] = __builtin_amdgcn_mfma_f32_16x16x32_bf16(afr[mtl][k0], wC, accC[mtl], 0, 0, 0);
                    }
                }
                // epilogue (log2-domain): C rows are edges
                #pragma unroll
                for (int mtl = 0; mtl < 2; mtl++) {
                    const int mt = 2 * h + mtl;
                    const int gnode = node0g + mt;
                    unsigned mbits = (unsigned)(mball >> ((mt << 4) + (q << 2))) & 0xFu;
                    float partial = 0.0f;
                    #pragma unroll
                    for (int r = 0; r < 4; r++) {
                        bool msk = (mbits >> r) & 1u;
                        float f2 = accF[mtl][r];
                        float c2 = accC[mtl][r];
                        float sig = __builtin_amdgcn_rcpf(1.0f + __builtin_amdgcn_exp2f(-f2));
                        float sp2 = fmaxf(c2, 0.0f) +
                                    __builtin_amdgcn_logf(1.0f + __builtin_amdgcn_exp2f(-fabsf(c2)));
                        partial += msk ? sig * sp2 : 0.0f;
                    }
                    partial += __shfl_xor(partial, 16);
                    partial += __shfl_xor(partial, 32);
                    if (q == 0) {
                        // quartered store: quarter qs, node gnode, col ctl*16+ln16
                        nf_out[((size_t)qs * NNODES + gnode) * 32 + ctl * 16 + ln16] =
                            to_bf16(softplusf_(fmaf(alpha, svv[mtl][ctl], LN2_F * partial)));
                    }
                }
            }
        }
    }
}

// ---------- fallback conv layer (non-precomp path; unchanged) ----------
template<bool PRECOMP>
__global__ __launch_bounds__(256, 3) void k_conv_mfma(
    const __hip_bfloat16* __restrict__ nf_in,
    const float* __restrict__ edge_fea,
    const __hip_bfloat16* __restrict__ ef_bf,
    const int*   __restrict__ eidx,
    const float* __restrict__ WeT,
    const float* __restrict__ be,
    const __hip_bfloat16* __restrict__ Wb,
    const __hip_bfloat16* __restrict__ Wsb,
    const float* __restrict__ bias,
    const float* __restrict__ palpha,
    __hip_bfloat16* __restrict__ nf_out)
{
    __shared__ __align__(16) __hip_bfloat16 A_s[4 * K0C * 512];
    __shared__ __align__(16) __hip_bfloat16 A_sf[4 * 512];

    const int node0 = blockIdx.x * 4;
    const int b = node0 >> 8;
    const int t = threadIdx.x;
    const int wv = t >> 6, lane = t & 63;
    const int q = lane >> 4, ln16 = lane & 15;
    const int row = (wv << 4) + ln16;

    const int myidx = eidx[node0 * Mm + row];
    const unsigned long long mball = __ballot(eidx[node0 * Mm + lane] >= 0);

    float selfv[8];
    #pragma unroll
    for (int mt = 0; mt < 4; mt++)
        #pragma unroll
        for (int p = 0; p < 2; p++)
            selfv[mt * 2 + p] =
                __bfloat162float(nf_in[(size_t)(node0 + mt) * NF + (2 * wv + p) * 16 + ln16]);

    {
        int j = myidx < 0 ? 0 : myidx;
        const __hip_bfloat16* gathp = nf_in + (size_t)((b << 8) + j) * NF;
        #pragma unroll
        for (int k0 = 0; k0 < 4; k0++)
            *(uint4*)(A_s + ((wv * K0C + k0) * 64 + lane) * 8) =
                *(const uint4*)(gathp + k0 * 32 + q * 8);
        *(uint4*)(A_sf + (wv * 64 + lane) * 8) =
            *(const uint4*)(nf_in + (size_t)(node0 + (ln16 & 3)) * NF + wv * 32 + q * 8);
        if (PRECOMP) {
            const __hip_bfloat16* efp = ef_bf + (size_t)((node0 << 4) + row) * EF;
            #pragma unroll
            for (int k0 = 0; k0 < 2; k0++)
                *(uint4*)(A_s + ((wv * K0C + 4 + k0) * 64 + lane) * 8) =
                    *(const uint4*)(efp + k0 * 32 + q * 8);
        } else {
            for (int c = t; c < 64 * EF; c += 256) {
                int rr = c >> 6, col = c & 63;
                float a = be[col];
                const float* er = edge_fea + (size_t)(node0 * Mm + rr) * OEF;
                #pragma unroll
                for (int i = 0; i < OEF; i++) a = fmaf(er[i], WeT[i * EF + col], a);
                int mt = rr >> 4, l16 = rr & 15;
                int k0 = 4 + (col >> 5), qq = (col >> 3) & 3, jj = col & 7;
                A_s[((mt * K0C + k0) * 64 + qq * 16 + l16) * 8 + jj] = to_bf16(a);
            }
        }
    }
    __syncthreads();

    f32x4 sv[4];
    #pragma unroll
    for (int c = 0; c < 4; c++) {
        int tile = 2 * wv + (c & 1) + ((c >> 1) << 3);
        float bv = bias[tile * 16 + ln16] * LOG2E_F;
        sv[c] = (f32x4){bv, bv, bv, bv};
    }
    #pragma unroll
    for (int k0 = 0; k0 < 4; k0++) {
        short8 afs = *(const short8*)(A_sf + (k0 * 64 + lane) * 8);
        #pragma unroll
        for (int c = 0; c < 4; c++) {
            int tile = 2 * wv + (c & 1) + ((c >> 1) << 3);
            short8 bws = *(const short8*)(Wsb + ((size_t)(tile * 4 + k0) << 9) + (lane << 3));
            sv[c] = __builtin_amdgcn_mfma_f32_16x16x32_bf16(afs, bws, sv[c], 0, 0, 0);
        }
    }

    f32x4 accF[4][2], accC[4][2];
    #pragma unroll
    for (int mt = 0; mt < 4; mt++) {
        #pragma unroll
        for (int p = 0; p < 2; p++) {
            float vF = __shfl(sv[p][mt], ln16);
            float vC = __shfl(sv[2 + p][mt], ln16);
            accF[mt][p] = (f32x4){vF, vF, vF, vF};
            accC[mt][p] = (f32x4){vC, vC, vC, vC};
        }
    }

    const __hip_bfloat16* WF0 = Wb + ((size_t)(2 * wv) * (K0C * 512)) + (lane << 3);
    const __hip_bfloat16* WF1 = WF0 + K0C * 512;
    const __hip_bfloat16* WC0 = WF0 + 8 * (K0C * 512);
    const __hip_bfloat16* WC1 = WC0 + K0C * 512;

    #pragma unroll
    for (int k0 = 0; k0 < K0C; k0++) {
        short8 cF0 = *(const short8*)(WF0 + k0 * 512);
        short8 cF1 = *(const short8*)(WF1 + k0 * 512);
        short8 cC0 = *(const short8*)(WC0 + k0 * 512);
        short8 cC1 = *(const short8*)(WC1 + k0 * 512);
        short8 af[4];
        #pragma unroll
        for (int mt = 0; mt < 4; mt++)
            af[mt] = *(const short8*)(A_s + ((mt * K0C + k0) * 64 + lane) * 8);
        #pragma unroll
        for (int mt = 0; mt < 4; mt++) {
            accF[mt][0] = __builtin_amdgcn_mfma_f32_16x16x32_bf16(af[mt], cF0, accF[mt][0], 0, 0, 0);
            accF[mt][1] = __builtin_amdgcn_mfma_f32_16x16x32_bf16(af[mt], cF1, accF[mt][1], 0, 0, 0);
            accC[mt][0] = __builtin_amdgcn_mfma_f32_16x16x32_bf16(af[mt], cC0, accC[mt][0], 0, 0, 0);
            accC[mt][1] = __builtin_amdgcn_mfma_f32_16x16x32_bf16(af[mt], cC1, accC[mt][1], 0, 0, 0);
        }
    }

    const float alpha = *palpha;
    #pragma unroll
    for (int mt = 0; mt < 4; mt++) {
        const int gnode = node0 + mt;
        unsigned mbits = (unsigned)(mball >> (mt * 16 + q * 4)) & 0xFu;
        #pragma unroll
        for (int p = 0; p < 2; p++) {
            float partial = 0.0f;
            #pragma unroll
            for (int r = 0; r < 4; r++) {
                bool msk = (mbits >> r) & 1u;
                float f2 = accF[mt][p][r];
                float c2 = accC[mt][p][r];
                float sig = __builtin_amdgcn_rcpf(1.0f + __builtin_amdgcn_exp2f(-f2));
                float sp2 = fmaxf(c2, 0.0f) +
                            __builtin_amdgcn_logf(1.0f + __builtin_amdgcn_exp2f(-fabsf(c2)));
                partial += msk ? sig * sp2 : 0.0f;
            }
            partial += __shfl_xor(partial, 16);
            partial += __shfl_xor(partial, 32);
            if (q == 0) {
                int col = (2 * wv + p) * 16 + ln16;
                nf_out[(size_t)gnode * NF + col] =
                    to_bf16(softplusf_(fmaf(alpha, selfv[mt * 2 + p], LN2_F * partial)));
            }
        }
    }
}

// ---------- final linear (MFMA): out[:, :, 0:64] = nf3 @ Wf^T + bf ----------
// QIN=true: nf is quartered [4][NNODES][32].
template<bool QIN>
__global__ __launch_bounds__(256) void k_final_mfma(
    const __hip_bfloat16* __restrict__ nf, const __hip_bfloat16* __restrict__ Wfb,
    const float* __restrict__ bfv, float* __restrict__ out,
    __hip_bfloat16* __restrict__ XT)
{
    __shared__ __align__(16) __hip_bfloat16 A_s[16 * 512];
    const int node0 = blockIdx.x * 64;
    const int bloc = node0 >> 8;
    const int t = threadIdx.x;
    const int wv = t >> 6, lane = t & 63;
    const int q = lane >> 4, ln16 = lane & 15;

    const int node = node0 + (wv << 4) + ln16;
    #pragma unroll
    for (int k0 = 0; k0 < 4; k0++) {
        const __hip_bfloat16* src = QIN
            ? nf + ((size_t)k0 * NNODES + node) * 32 + q * 8
            : nf + (size_t)node * NF + k0 * 32 + q * 8;
        *(uint4*)(A_s + ((wv * 4 + k0) * 64 + lane) * 8) = *(const uint4*)src;
    }
    __syncthreads();

    short8 bw[4];
    #pragma unroll
    for (int k0 = 0; k0 < 4; k0++)
        bw[k0] = *(const short8*)(Wfb + ((size_t)(wv * 4 + k0) * 64 + lane) * 8);

    float bv = bfv[wv * 16 + ln16];
    f32x4 acc[4];
    #pragma unroll
    for (int mt = 0; mt < 4; mt++) acc[mt] = (f32x4){bv, bv, bv, bv};

    #pragma unroll
    for (int k0 = 0; k0 < 4; k0++) {
        short8 af[4];
        #pragma unroll
        for (int mt = 0; mt < 4; mt++)
            af[mt] = *(const short8*)(A_s + ((mt * 4 + k0) * 64 + lane) * 8);
        #pragma unroll
        for (int mt = 0; mt < 4; mt++)
            acc[mt] = __builtin_amdgcn_mfma_f32_16x16x32_bf16(af[mt], bw[k0], acc[mt], 0, 0, 0);
    }

    const int col = (wv << 4) + ln16;
    #pragma unroll
    for (int mt = 0; mt < 4; mt++)
        #pragma unroll
        for (int r = 0; r < 4; r++) {
            int row = mt * 16 + q * 4 + r;
            float v = acc[mt][r];
            out[(size_t)(node0 + row) * FINAL + col] = v;
            XT[(size_t)(bloc * 64 + col) * 256 + (node0 & 255) + row] = to_bf16(v);
        }
}

// ---------- node1 (MFMA): out[:, :, 64:128] = DA @ nff per batch ----------
__global__ __launch_bounds__(256) void k_node1_mfma(
    const __hip_bfloat16* __restrict__ DAf,
    const __hip_bfloat16* __restrict__ XT,
    float* __restrict__ out)
{
    __shared__ __align__(16) __hip_bfloat16 B_s[32 * 512];
    const int blk = blockIdx.x;
    const int b = blk >> 2, i0 = (blk & 3) * 64;
    const int t = threadIdx.x;
    const int wv = t >> 6, lane = t & 63;
    const int q = lane >> 4, ln16 = lane & 15;

    const __hip_bfloat16* xrow = XT + (size_t)(b * 64 + (wv << 4) + ln16) * 256;
    #pragma unroll
    for (int k0 = 0; k0 < 8; k0++)
        *(uint4*)(B_s + ((wv * 8 + k0) * 64 + lane) * 8) =
            *(const uint4*)(xrow + k0 * 32 + q * 8);
    __syncthreads();

    f32x4 acc[4];
    #pragma unroll
    for (int mt = 0; mt < 4; mt++) acc[mt] = (f32x4){0.f, 0.f, 0.f, 0.f};

    #pragma unroll
    for (int k0 = 0; k0 < 8; k0++) {
        short8 bfr = *(const short8*)(B_s + ((wv * 8 + k0) * 64 + lane) * 8);
        short8 af[4];
        #pragma unroll
        for (int mt = 0; mt < 4; mt++)
            af[mt] = *(const short8*)(DAf + (size_t)(((i0 >> 4) + mt) * 8 + k0) * 512 + (lane << 3));
        #pragma unroll
        for (int mt = 0; mt < 4; mt++)
            acc[mt] = __builtin_amdgcn_mfma_f32_16x16x32_bf16(af[mt], bfr, acc[mt], 0, 0, 0);
    }

    #pragma unroll
    for (int mt = 0; mt < 4; mt++)
        #pragma unroll
        for (int r = 0; r < 4; r++) {
            int i = i0 + mt * 16 + q * 4 + r;
            out[(size_t)((b << 8) + i) * FINAL + 64 + (wv << 4) + ln16] = acc[mt][r];
        }
}

extern "C" void kernel_launch(void* const* d_in, const int* in_sizes, int n_in,
                              void* d_out, int out_size, void* d_ws, size_t ws_size,
                              hipStream_t stream)
{
    const float* node_fea = (const float*)d_in[0];
    const float* edge_fea = (const float*)d_in[1];
    const int*   eidx     = (const int*)  d_in[2];
    const float* dis      = (const float*)d_in[3];
    const float* Wn = (const float*)d_in[4];
    const float* bn = (const float*)d_in[5];
    const float* We = (const float*)d_in[6];
    const float* be = (const float*)d_in[7];
    const float* W1 = (const float*)d_in[8];
    const float* b1 = (const float*)d_in[9];
    const float* a1 = (const float*)d_in[10];
    const float* W2 = (const float*)d_in[11];
    const float* b2 = (const float*)d_in[12];
    const float* a2 = (const float*)d_in[13];
    const float* W3 = (const float*)d_in[14];
    const float* b3 = (const float*)d_in[15];
    const float* a3 = (const float*)d_in[16];
    const float* Wf = (const float*)d_in[17];
    const float* bf = (const float*)d_in[18];
    const float* DAw = (const float*)d_in[19];
    const float* DAb = (const float*)d_in[20];
    float* out = (float*)d_out;

    // workspace layout (bytes, 256-aligned blocks)
    char* base = (char*)d_ws;
    size_t off = 0;
    auto alloc = [&](size_t bytes) { char* p = base + off; off = (off + bytes + 255) & ~(size_t)255; return p; };
    __hip_bfloat16* nfA = (__hip_bfloat16*)alloc((size_t)Bb * Nn * NF * 2);
    __hip_bfloat16* nfB = (__hip_bfloat16*)alloc((size_t)Bb * Nn * NF * 2);
    __hip_bfloat16* W1b = (__hip_bfloat16*)alloc((size_t)SZ_WB * 2);
    __hip_bfloat16* W2b = (__hip_bfloat16*)alloc((size_t)SZ_WB * 2);
    __hip_bfloat16* W3b = (__hip_bfloat16*)alloc((size_t)SZ_WB * 2);
    __hip_bfloat16* W1s = (__hip_bfloat16*)alloc((size_t)SZ_WS * 2);
    __hip_bfloat16* W2s = (__hip_bfloat16*)alloc((size_t)SZ_WS * 2);
    __hip_bfloat16* W3s = (__hip_bfloat16*)alloc((size_t)SZ_WS * 2);
    float* WeT = (float*)alloc((size_t)OEF * EF * 4);
    __hip_bfloat16* DAf = (__hip_bfloat16*)alloc((size_t)Nn * Nn * 2);
    __hip_bfloat16* Wnb = (__hip_bfloat16*)alloc((size_t)SZ_WNB * 2);
    __hip_bfloat16* Web = (__hip_bfloat16*)alloc((size_t)SZ_WEB * 2);
    __hip_bfloat16* Wfb = (__hip_bfloat16*)alloc((size_t)SZ_WFB * 2);
    __hip_bfloat16* XT  = (__hip_bfloat16*)alloc((size_t)Bb * 64 * Nn * 2);
    __hip_bfloat16* efb = (__hip_bfloat16*)alloc((size_t)Bb * Nn * Mm * EF * 2);    // 33.5 MB
    float* Sbuf = (float*)alloc((size_t)Bb * Nn * ODIM * 4);                        // 16.8 MB
    __hip_bfloat16* QA = (__hip_bfloat16*)alloc((size_t)NNODES * NF * 2);           // 4 MB quartered
    __hip_bfloat16* QB = (__hip_bfloat16*)alloc((size_t)NNODES * NF * 2);           // 4 MB quartered
    const bool precomp = (ws_size >= off);

    hipLaunchKernelGGL(k_prep, dim3((PREP_TOTAL + 255) / 256), dim3(256), 0, stream,
                       We, W1, W2, W3, Wn, Wf, dis, DAw, DAb,
                       WeT, W1b, W2b, W3b, W1s, W2s, W3s, Wnb, Web, Wfb, DAf);

    hipLaunchKernelGGL(k_embed_all, dim3(precomp ? (256 + Bb * Nn * Mm / 64) : 256), dim3(256), 0, stream,
                       node_fea, Wnb, bn, nfA, edge_fea, Web, be, efb);

    if (precomp) {
        hipLaunchKernelGGL((k_gemm_s<false>), dim3(Bb * Nn / 64), dim3(256), 0, stream,
                           nfA, W1s, b1, Sbuf);
        hipLaunchKernelGGL((k_conv_q<false>), dim3(2048), dim3(256), 0, stream,
                           nfA, efb, eidx, W1b, Sbuf, a1, QA);
        hipLaunchKernelGGL((k_gemm_s<true>), dim3(Bb * Nn / 64), dim3(256), 0, stream,
                           QA, W2s, b2, Sbuf);
        hipLaunchKernelGGL((k_conv_q<true>), dim3(2048), dim3(256), 0, stream,
                           QA, efb, eidx, W2b, Sbuf, a2, QB);
        hipLaunchKernelGGL((k_gemm_s<true>), dim3(Bb * Nn / 64), dim3(256), 0, stream,
                           QB, W3s, b3, Sbuf);
        hipLaunchKernelGGL((k_conv_q<true>), dim3(2048), dim3(256), 0, stream,
                           QB, efb, eidx, W3b, Sbuf, a3, QA);
        hipLaunchKernelGGL((k_final_mfma<true>), dim3(Bb * Nn / 64), dim3(256), 0, stream,
                           QA, Wfb, bf, out, XT);
    } else {
        hipLaunchKernelGGL((k_conv_mfma<false>), dim3(Bb * Nn / 4), dim3(256), 0, stream,
                           nfA, edge_fea, efb, eidx, WeT, be, W1b, W1s, b1, a1, nfB);
        hipLaunchKernelGGL((k_conv_mfma<false>), dim3(Bb * Nn / 4), dim3(256), 0, stream,
                           nfB, edge_fea, efb, eidx, WeT, be, W2b, W2s, b2, a2, nfA);
        hipLaunchKernelGGL((k_conv_mfma<false>), dim3(Bb * Nn / 4), dim3(256), 0, stream,
                           nfA, edge_fea, efb, eidx, WeT, be, W3b, W3s, b3, a3, nfB);
        hipLaunchKernelGGL((k_final_mfma<false>), dim3(Bb * Nn / 64), dim3(256), 0, stream,
                           nfB, Wfb, bf, out, XT);
    }

    hipLaunchKernelGGL(k_node1_mfma, dim3(Bb * 4), dim3(256), 0, stream, DAf, XT, out);
}

// Round 10
// 331.843 us; speedup vs baseline: 1.1816x; 1.1816x over previous
//
#include <hip/hip_runtime.h>
#include <hip/hip_bf16.h>
#include <math.h>

#define Bb   64
#define Nn   256
#define Mm   16
#define ONF  92
#define OEF  41
#define NF   128
#define EF   64
#define KDIM 320   // 2*NF + EF
#define ODIM 256   // 2*NF
#define FINAL 128
#define K0C  6     // conv K-chunks (K=192: gather 128 + edge 64)
#define NNODES (Bb * Nn)   // 16384

#define LOG2E_F 1.44269504088896f
#define LN2_F   0.6931471805599453f

typedef __attribute__((ext_vector_type(8))) short short8;
typedef __attribute__((ext_vector_type(4))) float f32x4;

#define AS1 __attribute__((address_space(1)))
#define AS3 __attribute__((address_space(3)))

// async global->LDS DMA, 16B per lane. LDS dest = wave-uniform base + lane*16;
// global source is per-lane. Drained by the vmcnt(0) implicit in __syncthreads().
__device__ __forceinline__ void gl2lds16(const void* gp, void* lp) {
    __builtin_amdgcn_global_load_lds((AS1 void*)(void*)gp, (AS3 void*)lp, 16, 0, 0);
}

__device__ __forceinline__ float sigmoidf_(float x) {
    float e = __expf(-x);
    return __builtin_amdgcn_rcpf(1.0f + e);
}
__device__ __forceinline__ float softplusf_(float x) {
    return fmaxf(x, 0.0f) + __logf(1.0f + __expf(-fabsf(x)));
}
__device__ __forceinline__ __hip_bfloat16 to_bf16(float x) { return __float2bfloat16(x); }

// ---------- mega-prep: all weight swizzles + WeT + DA in ONE launch ----------
__device__ __forceinline__ void swz(const float* __restrict__ in, __hip_bfloat16* __restrict__ out,
                                    int t, int Itot, int koff, int Kuse, int K0, float scale)
{
    int j = t & 7;
    int u = t >> 3;
    int lane = u & 63;
    int ln16 = lane & 15, q = lane >> 4;
    int v = u >> 6;
    int k0 = v % K0, tile = v / K0;
    int n = tile * 16 + ln16, k = k0 * 32 + q * 8 + j;
    out[t] = (k < Kuse) ? to_bf16(scale * in[(size_t)n * Itot + koff + k]) : to_bf16(0.0f);
}

#define SZ_WET (OEF * EF)          // 2624
#define SZ_WB  (16 * K0C * 512)    // 49152
#define SZ_WS  (16 * 4 * 512)      // 32768
#define SZ_WNB ((NF / 16) * 3 * 512)
#define SZ_WEB ((EF / 16) * 2 * 512)
#define SZ_WFB ((64 / 16) * 4 * 512)
#define SZ_DA  (Nn * Nn)
#define PREP_TOTAL (SZ_WET + 3 * SZ_WB + 3 * SZ_WS + SZ_WNB + SZ_WEB + SZ_WFB + SZ_DA)

__global__ __launch_bounds__(256) void k_prep(
    const float* __restrict__ We, const float* __restrict__ W1,
    const float* __restrict__ W2, const float* __restrict__ W3,
    const float* __restrict__ Wn, const float* __restrict__ Wf,
    const float* __restrict__ dis, const float* __restrict__ pw, const float* __restrict__ pb,
    float* __restrict__ WeT,
    __hip_bfloat16* __restrict__ W1b, __hip_bfloat16* __restrict__ W2b, __hip_bfloat16* __restrict__ W3b,
    __hip_bfloat16* __restrict__ W1s, __hip_bfloat16* __restrict__ W2s, __hip_bfloat16* __restrict__ W3s,
    __hip_bfloat16* __restrict__ Wnb, __hip_bfloat16* __restrict__ Web, __hip_bfloat16* __restrict__ Wfb,
    __hip_bfloat16* __restrict__ DAf)
{
    int t = blockIdx.x * 256 + threadIdx.x;
    if (t < SZ_WET) {
        int o = t / OEF, i = t - o * OEF;
        WeT[i * EF + o] = We[t];
        return;
    }
    t -= SZ_WET;
    if (t < SZ_WB) { swz(W1, W1b, t, KDIM, NF, 192, K0C, LOG2E_F); return; }
    t -= SZ_WB;
    if (t < SZ_WB) { swz(W2, W2b, t, KDIM, NF, 192, K0C, LOG2E_F); return; }
    t -= SZ_WB;
    if (t < SZ_WB) { swz(W3, W3b, t, KDIM, NF, 192, K0C, LOG2E_F); return; }
    t -= SZ_WB;
    if (t < SZ_WS) { swz(W1, W1s, t, KDIM, 0, NF, 4, LOG2E_F); return; }
    t -= SZ_WS;
    if (t < SZ_WS) { swz(W2, W2s, t, KDIM, 0, NF, 4, LOG2E_F); return; }
    t -= SZ_WS;
    if (t < SZ_WS) { swz(W3, W3s, t, KDIM, 0, NF, 4, LOG2E_F); return; }
    t -= SZ_WS;
    if (t < SZ_WNB) { swz(Wn, Wnb, t, ONF, 0, ONF, 3, 1.0f); return; }
    t -= SZ_WNB;
    if (t < SZ_WEB) { swz(We, Web, t, OEF, 0, OEF, 2, 1.0f); return; }
    t -= SZ_WEB;
    if (t < SZ_WFB) { swz(Wf, Wfb, t, NF, 0, NF, 4, 1.0f); return; }
    t -= SZ_WFB;
    if (t < SZ_DA) {
        int i = t >> 8, jx = t & 255;
        float v = sigmoidf_(fmaf(*pw, dis[t], *pb));
        int itile = i >> 4, ln16 = i & 15;
        int k0 = jx >> 5, q = (jx >> 3) & 3, jj = jx & 7;
        DAf[(size_t)((((itile * 8 + k0) << 6) + (q << 4) + ln16)) * 8 + jj] = to_bf16(v);
    }
}

// ---------- generic MFMA embed body ----------
template<int KIN, int K0, int NCOLS>
__device__ __forceinline__ void emb_body(
    int bid, const float* __restrict__ X, const __hip_bfloat16* __restrict__ Bswz,
    const float* __restrict__ bias, __hip_bfloat16* __restrict__ Y,
    __hip_bfloat16* A_s, __hip_bfloat16* O_s)
{
    constexpr int KP = K0 * 32;
    constexpr int TPW = NCOLS / 64;
    constexpr int OLD = NCOLS + 24;

    const int row0 = bid * 64;
    const int t = threadIdx.x;

    {
        const float4* Xb = (const float4*)(X + (size_t)row0 * KIN);
        constexpr int NV = (64 * KIN) / 4;
        for (int c = t; c < NV; c += 256) {
            float4 v = Xb[c];
            int flat = c * 4;
            #pragma unroll
            for (int e = 0; e < 4; e++) {
                int f = flat + e;
                int row = f / KIN, k = f - row * KIN;
                int mt = row >> 4, ln16 = row & 15;
                int k0 = k >> 5, q = (k >> 3) & 3, j = k & 7;
                float vv = (e == 0) ? v.x : (e == 1) ? v.y : (e == 2) ? v.z : v.w;
                A_s[(((mt * K0 + k0) << 6) + (q << 4) + ln16) * 8 + j] = to_bf16(vv);
            }
        }
        constexpr int PAD = KP - KIN;
        for (int c = t; c < 64 * PAD; c += 256) {
            int row = c / PAD, k = KIN + (c - row * PAD);
            int mt = row >> 4, ln16 = row & 15;
            int k0 = k >> 5, q = (k >> 3) & 3, j = k & 7;
            A_s[(((mt * K0 + k0) << 6) + (q << 4) + ln16) * 8 + j] = to_bf16(0.0f);
        }
    }
    __syncthreads();

    const int wv = t >> 6, lane = t & 63;
    const int q = lane >> 4, ln16 = lane & 15;

    f32x4 acc[4][TPW];
    #pragma unroll
    for (int p = 0; p < TPW; p++) {
        float bv = bias[(wv * TPW + p) * 16 + ln16];
        #pragma unroll
        for (int mt = 0; mt < 4; mt++) acc[mt][p] = (f32x4){bv, bv, bv, bv};
    }

    short8 bw[TPW][K0];
    #pragma unroll
    for (int p = 0; p < TPW; p++)
        #pragma unroll
        for (int k0 = 0; k0 < K0; k0++)
            bw[p][k0] = *(const short8*)(Bswz + ((size_t)((wv * TPW + p) * K0 + k0) << 9) + (lane << 3));

    #pragma unroll
    for (int k0 = 0; k0 < K0; k0++) {
        short8 af[4];
        #pragma unroll
        for (int mt = 0; mt < 4; mt++)
            af[mt] = *(const short8*)(A_s + (((mt * K0 + k0) << 6) + lane) * 8);
        #pragma unroll
        for (int mt = 0; mt < 4; mt++)
            #pragma unroll
            for (int p = 0; p < TPW; p++)
                acc[mt][p] = __builtin_amdgcn_mfma_f32_16x16x32_bf16(af[mt], bw[p][k0], acc[mt][p], 0, 0, 0);
    }

    #pragma unroll
    for (int mt = 0; mt < 4; mt++)
        #pragma unroll
        for (int p = 0; p < TPW; p++) {
            int col = (wv * TPW + p) * 16 + ln16;
            #pragma unroll
            for (int r = 0; r < 4; r++)
                O_s[(mt * 16 + q * 4 + r) * OLD + col] = to_bf16(acc[mt][p][r]);
        }
    __syncthreads();
    constexpr int CH = NCOLS / 8;
    for (int c = t; c < 64 * CH; c += 256) {
        int row = c / CH, ch = c - row * CH;
        *(uint4*)(Y + (size_t)(row0 + row) * NCOLS + ch * 8) =
            *(const uint4*)(O_s + row * OLD + ch * 8);
    }
}

// blocks [0,256): node embed; [256, 256+4096): edge embed
__global__ __launch_bounds__(256) void k_embed_all(
    const float* __restrict__ node_fea, const __hip_bfloat16* __restrict__ Wnb,
    const float* __restrict__ bn, __hip_bfloat16* __restrict__ nf0,
    const float* __restrict__ edge_fea, const __hip_bfloat16* __restrict__ Web,
    const float* __restrict__ be, __hip_bfloat16* __restrict__ efb)
{
    __shared__ __align__(16) __hip_bfloat16 A_s[4 * 3 * 512];
    __shared__ __align__(16) __hip_bfloat16 O_s[64 * (NF + 24)];
    if (blockIdx.x < 256)
        emb_body<ONF, 3, NF>(blockIdx.x, node_fea, Wnb, bn, nf0, A_s, O_s);
    else
        emb_body<OEF, 2, EF>(blockIdx.x - 256, edge_fea, Web, be, efb, A_s, O_s);
}

// ---------- S GEMM: S[n][o] = log2e*(nf[n] @ Wself[o] + bias[o]), f32 out ----------
// QIN=false: nf is standard [node][128]. QIN=true: quartered [4][NNODES][32].
template<bool QIN>
__global__ __launch_bounds__(256) void k_gemm_s(
    const __hip_bfloat16* __restrict__ nf,
    const __hip_bfloat16* __restrict__ Ws,
    const float* __restrict__ bias,
    float* __restrict__ S)
{
    __shared__ __align__(16) __hip_bfloat16 A_s[16 * 512];
    const int row0 = blockIdx.x * 64;
    const int t = threadIdx.x;
    const int wv = t >> 6, lane = t & 63;
    const int q = lane >> 4, ln16 = lane & 15;

    #pragma unroll
    for (int k0 = 0; k0 < 4; k0++) {
        const int node = row0 + (wv << 4) + ln16;
        const __hip_bfloat16* src = QIN
            ? nf + ((size_t)k0 * NNODES + node) * 32 + q * 8
            : nf + (size_t)node * NF + k0 * 32 + q * 8;
        gl2lds16(src, A_s + ((wv * 4 + k0) * 64 + lane) * 8);
    }
    __syncthreads();

    short8 bw[4][4];
    #pragma unroll
    for (int p = 0; p < 4; p++)
        #pragma unroll
        for (int k0 = 0; k0 < 4; k0++)
            bw[p][k0] = *(const short8*)(Ws + ((size_t)((wv * 4 + p) * 4 + k0) << 9) + (lane << 3));

    f32x4 acc[4][4];
    #pragma unroll
    for (int p = 0; p < 4; p++) {
        float bv = bias[(wv * 4 + p) * 16 + ln16] * LOG2E_F;
        #pragma unroll
        for (int mt = 0; mt < 4; mt++) acc[mt][p] = (f32x4){bv, bv, bv, bv};
    }

    #pragma unroll
    for (int k0 = 0; k0 < 4; k0++) {
        short8 af[4];
        #pragma unroll
        for (int mt = 0; mt < 4; mt++)
            af[mt] = *(const short8*)(A_s + ((mt * 4 + k0) * 64 + lane) * 8);
        #pragma unroll
        for (int mt = 0; mt < 4; mt++)
            #pragma unroll
            for (int p = 0; p < 4; p++)
                acc[mt][p] = __builtin_amdgcn_mfma_f32_16x16x32_bf16(af[mt], bw[p][k0], acc[mt][p], 0, 0, 0);
    }

    #pragma unroll
    for (int mt = 0; mt < 4; mt++)
        #pragma unroll
        for (int p = 0; p < 4; p++) {
            int col = (wv * 4 + p) * 16 + ln16;
            #pragma unroll
            for (int r = 0; r < 4; r++)
                S[(size_t)(row0 + mt * 16 + q * 4 + r) * ODIM + col] = acc[mt][p][r];
        }
}

// ---------- conv layer R10: per-node processing, spill-free at 5 blocks/CU ----------
// R7-R9 plateau root-cause: launch_bounds(256,5) caps unified VGPR+AGPR at ~96;
// the 2-node body (afr[2][6]=48 + accs 32 + rest ~50) didn't fit -> compiler
// allocated 48+48 and SPILLED to scratch: ~120MB/dispatch HBM writes (WRITE_SIZE
// invariant across R7/R8/R9 layout changes = the tell). R10 shrinks the live set:
// process ONE node at a time (afr[6]=24 regs, reused across both ctl), accs per
// (node,ctl)=8 regs. Live ~60-75 < 96 -> no spill, 5 blocks/CU real. Cost:
// weight ds_reads 2x (192/wave, ~10us/layer LDS BW chip-wide, overlapped).
template<bool QIN>
__global__ __launch_bounds__(256, 5) void k_conv_q(
    const __hip_bfloat16* __restrict__ nf_in,   // std [node][128] or quartered
    const __hip_bfloat16* __restrict__ ef_bf,   // [B*N*M][EF] bf16
    const int*   __restrict__ eidx,             // [B*N][16]
    const __hip_bfloat16* __restrict__ Wb,      // [16][K0C][512] (log2e*W[:,128:320])
    const float* __restrict__ Sbuf,             // [B*N][ODIM] f32 = log2e*(self+bias)
    const float* __restrict__ palpha,
    __hip_bfloat16* __restrict__ nf_out)        // quartered [4][NNODES][32] bf16
{
    __shared__ __align__(16) __hip_bfloat16 Wl[4 * K0C * 512];   // 24576 B

    const int t = threadIdx.x;
    const int wv = t >> 6, lane = t & 63;
    const int q = lane >> 4, ln16 = lane & 15;
    const int qs = (blockIdx.x >> 3) & 3;        // column quarter (XCD-safe bits)
    const int gb = ((blockIdx.x >> 5) << 3) | (blockIdx.x & 7);  // group octet 0..511
    const float alpha = *palpha;

    // ---- stage 4 weight tiles (1536 chunks of 16B; 6 per thread; dest linear)
    #pragma unroll
    for (int p = 0; p < 6; p++) {
        int idx = p * 256 + t;
        int tll = idx / 384;                     // local tile 0..3 (384 chunks each)
        int cin = idx - tll * 384;
        int gt = (tll < 2) ? (2 * qs + tll) : (8 + 2 * qs + (tll - 2));
        gl2lds16(Wb + (size_t)gt * (K0C * 512) + cin * 8, Wl + (size_t)idx * 8);
    }
    __syncthreads();   // the ONLY barrier; waves free-run below

    #pragma unroll 1
    for (int task = 0; task < 2; task++) {
        const int g = gb * 8 + (task << 2) + wv;      // group of 4 nodes
        const int node0g = g * 4;
        const int bbase = node0g & ~255;
        const int jv = eidx[(node0g << 4) + lane];    // lane = edge slot in group
        const unsigned long long mball = __ballot(jv >= 0);

        // ---- per node: afr[6] (24 regs) loaded once, reused across both ctl
        #pragma unroll 1
        for (int mt = 0; mt < 4; mt++) {
            const int gnode = node0g + mt;
            int jm = __shfl(jv, (mt << 4) + ln16);
            jm = jm < 0 ? 0 : jm;

            short8 afr[K0C];
            #pragma unroll
            for (int k0 = 0; k0 < 4; k0++) {
                const __hip_bfloat16* gp = QIN
                    ? nf_in + ((size_t)k0 * NNODES + (bbase + jm)) * 32 + q * 8
                    : nf_in + (size_t)(bbase + jm) * NF + k0 * 32 + q * 8;
                afr[k0] = *(const short8*)gp;
            }
            const __hip_bfloat16* ep =
                ef_bf + ((size_t)(gnode << 4) + ln16) * EF + q * 8;
            afr[4] = *(const short8*)(ep);
            afr[5] = *(const short8*)(ep + 32);

            const float* Sr = Sbuf + (size_t)gnode * ODIM + qs * 32 + ln16;
            const __hip_bfloat16* nr = QIN
                ? nf_in + ((size_t)qs * NNODES + gnode) * 32 + ln16
                : nf_in + (size_t)gnode * NF + qs * 32 + ln16;
            const unsigned mbits = (unsigned)(mball >> ((mt << 4) + (q << 2))) & 0xFu;

            #pragma unroll 1
            for (int ctl = 0; ctl < 2; ctl++) {
                float vF = Sr[ctl * 16];
                float vC = Sr[128 + ctl * 16];
                f32x4 accF = (f32x4){vF, vF, vF, vF};
                f32x4 accC = (f32x4){vC, vC, vC, vC};
                #pragma unroll
                for (int k0 = 0; k0 < K0C; k0++) {
                    short8 wF = *(const short8*)(Wl + (((ctl)     * K0C + k0) << 9) + (lane << 3));
                    short8 wC = *(const short8*)(Wl + (((2 + ctl) * K0C + k0) << 9) + (lane << 3));
                    accF = __builtin_amdgcn_mfma_f32_16x16x32_bf16(afr[k0], wF, accF, 0, 0, 0);
                    accC = __builtin_amdgcn_mfma_f32_16x16x32_bf16(afr[k0], wC, accC, 0, 0, 0);
                }
                // epilogue (log2-domain): C rows are edges
                float partial = 0.0f;
                #pragma unroll
                for (int r = 0; r < 4; r++) {
                    bool msk = (mbits >> r) & 1u;
                    float f2 = accF[r];
                    float c2 = accC[r];
                    float sig = __builtin_amdgcn_rcpf(1.0f + __builtin_amdgcn_exp2f(-f2));
                    float sp2 = fmaxf(c2, 0.0f) +
                                __builtin_amdgcn_logf(1.0f + __builtin_amdgcn_exp2f(-fabsf(c2)));
                    partial += msk ? sig * sp2 : 0.0f;
                }
                partial += __shfl_xor(partial, 16);
                partial += __shfl_xor(partial, 32);
                if (q == 0) {
                    float svv = __bfloat162float(nr[ctl * 16]);
                    nf_out[((size_t)qs * NNODES + gnode) * 32 + ctl * 16 + ln16] =
                        to_bf16(softplusf_(fmaf(alpha, svv, LN2_F * partial)));
                }
            }
        }
    }
}

// ---------- fallback conv layer (non-precomp path; unchanged) ----------
template<bool PRECOMP>
__global__ __launch_bounds__(256, 3) void k_conv_mfma(
    const __hip_bfloat16* __restrict__ nf_in,
    const float* __restrict__ edge_fea,
    const __hip_bfloat16* __restrict__ ef_bf,
    const int*   __restrict__ eidx,
    const float* __restrict__ WeT,
    const float* __restrict__ be,
    const __hip_bfloat16* __restrict__ Wb,
    const __hip_bfloat16* __restrict__ Wsb,
    const float* __restrict__ bias,
    const float* __restrict__ palpha,
    __hip_bfloat16* __restrict__ nf_out)
{
    __shared__ __align__(16) __hip_bfloat16 A_s[4 * K0C * 512];
    __shared__ __align__(16) __hip_bfloat16 A_sf[4 * 512];

    const int node0 = blockIdx.x * 4;
    const int b = node0 >> 8;
    const int t = threadIdx.x;
    const int wv = t >> 6, lane = t & 63;
    const int q = lane >> 4, ln16 = lane & 15;
    const int row = (wv << 4) + ln16;

    const int myidx = eidx[node0 * Mm + row];
    const unsigned long long mball = __ballot(eidx[node0 * Mm + lane] >= 0);

    float selfv[8];
    #pragma unroll
    for (int mt = 0; mt < 4; mt++)
        #pragma unroll
        for (int p = 0; p < 2; p++)
            selfv[mt * 2 + p] =
                __bfloat162float(nf_in[(size_t)(node0 + mt) * NF + (2 * wv + p) * 16 + ln16]);

    {
        int j = myidx < 0 ? 0 : myidx;
        const __hip_bfloat16* gathp = nf_in + (size_t)((b << 8) + j) * NF;
        #pragma unroll
        for (int k0 = 0; k0 < 4; k0++)
            *(uint4*)(A_s + ((wv * K0C + k0) * 64 + lane) * 8) =
                *(const uint4*)(gathp + k0 * 32 + q * 8);
        *(uint4*)(A_sf + (wv * 64 + lane) * 8) =
            *(const uint4*)(nf_in + (size_t)(node0 + (ln16 & 3)) * NF + wv * 32 + q * 8);
        if (PRECOMP) {
            const __hip_bfloat16* efp = ef_bf + (size_t)((node0 << 4) + row) * EF;
            #pragma unroll
            for (int k0 = 0; k0 < 2; k0++)
                *(uint4*)(A_s + ((wv * K0C + 4 + k0) * 64 + lane) * 8) =
                    *(const uint4*)(efp + k0 * 32 + q * 8);
        } else {
            for (int c = t; c < 64 * EF; c += 256) {
                int rr = c >> 6, col = c & 63;
                float a = be[col];
                const float* er = edge_fea + (size_t)(node0 * Mm + rr) * OEF;
                #pragma unroll
                for (int i = 0; i < OEF; i++) a = fmaf(er[i], WeT[i * EF + col], a);
                int mt = rr >> 4, l16 = rr & 15;
                int k0 = 4 + (col >> 5), qq = (col >> 3) & 3, jj = col & 7;
                A_s[((mt * K0C + k0) * 64 + qq * 16 + l16) * 8 + jj] = to_bf16(a);
            }
        }
    }
    __syncthreads();

    f32x4 sv[4];
    #pragma unroll
    for (int c = 0; c < 4; c++) {
        int tile = 2 * wv + (c & 1) + ((c >> 1) << 3);
        float bv = bias[tile * 16 + ln16] * LOG2E_F;
        sv[c] = (f32x4){bv, bv, bv, bv};
    }
    #pragma unroll
    for (int k0 = 0; k0 < 4; k0++) {
        short8 afs = *(const short8*)(A_sf + (k0 * 64 + lane) * 8);
        #pragma unroll
        for (int c = 0; c < 4; c++) {
            int tile = 2 * wv + (c & 1) + ((c >> 1) << 3);
            short8 bws = *(const short8*)(Wsb + ((size_t)(tile * 4 + k0) << 9) + (lane << 3));
            sv[c] = __builtin_amdgcn_mfma_f32_16x16x32_bf16(afs, bws, sv[c], 0, 0, 0);
        }
    }

    f32x4 accF[4][2], accC[4][2];
    #pragma unroll
    for (int mt = 0; mt < 4; mt++) {
        #pragma unroll
        for (int p = 0; p < 2; p++) {
            float vF = __shfl(sv[p][mt], ln16);
            float vC = __shfl(sv[2 + p][mt], ln16);
            accF[mt][p] = (f32x4){vF, vF, vF, vF};
            accC[mt][p] = (f32x4){vC, vC, vC, vC};
        }
    }

    const __hip_bfloat16* WF0 = Wb + ((size_t)(2 * wv) * (K0C * 512)) + (lane << 3);
    const __hip_bfloat16* WF1 = WF0 + K0C * 512;
    const __hip_bfloat16* WC0 = WF0 + 8 * (K0C * 512);
    const __hip_bfloat16* WC1 = WC0 + K0C * 512;

    #pragma unroll
    for (int k0 = 0; k0 < K0C; k0++) {
        short8 cF0 = *(const short8*)(WF0 + k0 * 512);
        short8 cF1 = *(const short8*)(WF1 + k0 * 512);
        short8 cC0 = *(const short8*)(WC0 + k0 * 512);
        short8 cC1 = *(const short8*)(WC1 + k0 * 512);
        short8 af[4];
        #pragma unroll
        for (int mt = 0; mt < 4; mt++)
            af[mt] = *(const short8*)(A_s + ((mt * K0C + k0) * 64 + lane) * 8);
        #pragma unroll
        for (int mt = 0; mt < 4; mt++) {
            accF[mt][0] = __builtin_amdgcn_mfma_f32_16x16x32_bf16(af[mt], cF0, accF[mt][0], 0, 0, 0);
            accF[mt][1] = __builtin_amdgcn_mfma_f32_16x16x32_bf16(af[mt], cF1, accF[mt][1], 0, 0, 0);
            accC[mt][0] = __builtin_amdgcn_mfma_f32_16x16x32_bf16(af[mt], cC0, accC[mt][0], 0, 0, 0);
            accC[mt][1] = __builtin_amdgcn_mfma_f32_16x16x32_bf16(af[mt], cC1, accC[mt][1], 0, 0, 0);
        }
    }

    const float alpha = *palpha;
    #pragma unroll
    for (int mt = 0; mt < 4; mt++) {
        const int gnode = node0 + mt;
        unsigned mbits = (unsigned)(mball >> (mt * 16 + q * 4)) & 0xFu;
        #pragma unroll
        for (int p = 0; p < 2; p++) {
            float partial = 0.0f;
            #pragma unroll
            for (int r = 0; r < 4; r++) {
                bool msk = (mbits >> r) & 1u;
                float f2 = accF[mt][p][r];
                float c2 = accC[mt][p][r];
                float sig = __builtin_amdgcn_rcpf(1.0f + __builtin_amdgcn_exp2f(-f2));
                float sp2 = fmaxf(c2, 0.0f) +
                            __builtin_amdgcn_logf(1.0f + __builtin_amdgcn_exp2f(-fabsf(c2)));
                partial += msk ? sig * sp2 : 0.0f;
            }
            partial += __shfl_xor(partial, 16);
            partial += __shfl_xor(partial, 32);
            if (q == 0) {
                int col = (2 * wv + p) * 16 + ln16;
                nf_out[(size_t)gnode * NF + col] =
                    to_bf16(softplusf_(fmaf(alpha, selfv[mt * 2 + p], LN2_F * partial)));
            }
        }
    }
}

// ---------- final linear (MFMA): out[:, :, 0:64] = nf3 @ Wf^T + bf ----------
// QIN=true: nf is quartered [4][NNODES][32].
template<bool QIN>
__global__ __launch_bounds__(256) void k_final_mfma(
    const __hip_bfloat16* __restrict__ nf, const __hip_bfloat16* __restrict__ Wfb,
    const float* __restrict__ bfv, float* __restrict__ out,
    __hip_bfloat16* __restrict__ XT)
{
    __shared__ __align__(16) __hip_bfloat16 A_s[16 * 512];
    const int node0 = blockIdx.x * 64;
    const int bloc = node0 >> 8;
    const int t = threadIdx.x;
    const int wv = t >> 6, lane = t & 63;
    const int q = lane >> 4, ln16 = lane & 15;

    const int node = node0 + (wv << 4) + ln16;
    #pragma unroll
    for (int k0 = 0; k0 < 4; k0++) {
        const __hip_bfloat16* src = QIN
            ? nf + ((size_t)k0 * NNODES + node) * 32 + q * 8
            : nf + (size_t)node * NF + k0 * 32 + q * 8;
        *(uint4*)(A_s + ((wv * 4 + k0) * 64 + lane) * 8) = *(const uint4*)src;
    }
    __syncthreads();

    short8 bw[4];
    #pragma unroll
    for (int k0 = 0; k0 < 4; k0++)
        bw[k0] = *(const short8*)(Wfb + ((size_t)(wv * 4 + k0) * 64 + lane) * 8);

    float bv = bfv[wv * 16 + ln16];
    f32x4 acc[4];
    #pragma unroll
    for (int mt = 0; mt < 4; mt++) acc[mt] = (f32x4){bv, bv, bv, bv};

    #pragma unroll
    for (int k0 = 0; k0 < 4; k0++) {
        short8 af[4];
        #pragma unroll
        for (int mt = 0; mt < 4; mt++)
            af[mt] = *(const short8*)(A_s + ((mt * 4 + k0) * 64 + lane) * 8);
        #pragma unroll
        for (int mt = 0; mt < 4; mt++)
            acc[mt] = __builtin_amdgcn_mfma_f32_16x16x32_bf16(af[mt], bw[k0], acc[mt], 0, 0, 0);
    }

    const int col = (wv << 4) + ln16;
    #pragma unroll
    for (int mt = 0; mt < 4; mt++)
        #pragma unroll
        for (int r = 0; r < 4; r++) {
            int row = mt * 16 + q * 4 + r;
            float v = acc[mt][r];
            out[(size_t)(node0 + row) * FINAL + col] = v;
            XT[(size_t)(bloc * 64 + col) * 256 + (node0 & 255) + row] = to_bf16(v);
        }
}

// ---------- node1 (MFMA): out[:, :, 64:128] = DA @ nff per batch ----------
__global__ __launch_bounds__(256) void k_node1_mfma(
    const __hip_bfloat16* __restrict__ DAf,
    const __hip_bfloat16* __restrict__ XT,
    float* __restrict__ out)
{
    __shared__ __align__(16) __hip_bfloat16 B_s[32 * 512];
    const int blk = blockIdx.x;
    const int b = blk >> 2, i0 = (blk & 3) * 64;
    const int t = threadIdx.x;
    const int wv = t >> 6, lane = t & 63;
    const int q = lane >> 4, ln16 = lane & 15;

    const __hip_bfloat16* xrow = XT + (size_t)(b * 64 + (wv << 4) + ln16) * 256;
    #pragma unroll
    for (int k0 = 0; k0 < 8; k0++)
        *(uint4*)(B_s + ((wv * 8 + k0) * 64 + lane) * 8) =
            *(const uint4*)(xrow + k0 * 32 + q * 8);
    __syncthreads();

    f32x4 acc[4];
    #pragma unroll
    for (int mt = 0; mt < 4; mt++) acc[mt] = (f32x4){0.f, 0.f, 0.f, 0.f};

    #pragma unroll
    for (int k0 = 0; k0 < 8; k0++) {
        short8 bfr = *(const short8*)(B_s + ((wv * 8 + k0) * 64 + lane) * 8);
        short8 af[4];
        #pragma unroll
        for (int mt = 0; mt < 4; mt++)
            af[mt] = *(const short8*)(DAf + (size_t)(((i0 >> 4) + mt) * 8 + k0) * 512 + (lane << 3));
        #pragma unroll
        for (int mt = 0; mt < 4; mt++)
            acc[mt] = __builtin_amdgcn_mfma_f32_16x16x32_bf16(af[mt], bfr, acc[mt], 0, 0, 0);
    }

    #pragma unroll
    for (int mt = 0; mt < 4; mt++)
        #pragma unroll
        for (int r = 0; r < 4; r++) {
            int i = i0 + mt * 16 + q * 4 + r;
            out[(size_t)((b << 8) + i) * FINAL + 64 + (wv << 4) + ln16] = acc[mt][r];
        }
}

extern "C" void kernel_launch(void* const* d_in, const int* in_sizes, int n_in,
                              void* d_out, int out_size, void* d_ws, size_t ws_size,
                              hipStream_t stream)
{
    const float* node_fea = (const float*)d_in[0];
    const float* edge_fea = (const float*)d_in[1];
    const int*   eidx     = (const int*)  d_in[2];
    const float* dis      = (const float*)d_in[3];
    const float* Wn = (const float*)d_in[4];
    const float* bn = (const float*)d_in[5];
    const float* We = (const float*)d_in[6];
    const float* be = (const float*)d_in[7];
    const float* W1 = (const float*)d_in[8];
    const float* b1 = (const float*)d_in[9];
    const float* a1 = (const float*)d_in[10];
    const float* W2 = (const float*)d_in[11];
    const float* b2 = (const float*)d_in[12];
    const float* a2 = (const float*)d_in[13];
    const float* W3 = (const float*)d_in[14];
    const float* b3 = (const float*)d_in[15];
    const float* a3 = (const float*)d_in[16];
    const float* Wf = (const float*)d_in[17];
    const float* bf = (const float*)d_in[18];
    const float* DAw = (const float*)d_in[19];
    const float* DAb = (const float*)d_in[20];
    float* out = (float*)d_out;

    // workspace layout (bytes, 256-aligned blocks)
    char* base = (char*)d_ws;
    size_t off = 0;
    auto alloc = [&](size_t bytes) { char* p = base + off; off = (off + bytes + 255) & ~(size_t)255; return p; };
    __hip_bfloat16* nfA = (__hip_bfloat16*)alloc((size_t)Bb * Nn * NF * 2);
    __hip_bfloat16* nfB = (__hip_bfloat16*)alloc((size_t)Bb * Nn * NF * 2);
    __hip_bfloat16* W1b = (__hip_bfloat16*)alloc((size_t)SZ_WB * 2);
    __hip_bfloat16* W2b = (__hip_bfloat16*)alloc((size_t)SZ_WB * 2);
    __hip_bfloat16* W3b = (__hip_bfloat16*)alloc((size_t)SZ_WB * 2);
    __hip_bfloat16* W1s = (__hip_bfloat16*)alloc((size_t)SZ_WS * 2);
    __hip_bfloat16* W2s = (__hip_bfloat16*)alloc((size_t)SZ_WS * 2);
    __hip_bfloat16* W3s = (__hip_bfloat16*)alloc((size_t)SZ_WS * 2);
    float* WeT = (float*)alloc((size_t)OEF * EF * 4);
    __hip_bfloat16* DAf = (__hip_bfloat16*)alloc((size_t)Nn * Nn * 2);
    __hip_bfloat16* Wnb = (__hip_bfloat16*)alloc((size_t)SZ_WNB * 2);
    __hip_bfloat16* Web = (__hip_bfloat16*)alloc((size_t)SZ_WEB * 2);
    __hip_bfloat16* Wfb = (__hip_bfloat16*)alloc((size_t)SZ_WFB * 2);
    __hip_bfloat16* XT  = (__hip_bfloat16*)alloc((size_t)Bb * 64 * Nn * 2);
    __hip_bfloat16* efb = (__hip_bfloat16*)alloc((size_t)Bb * Nn * Mm * EF * 2);    // 33.5 MB
    float* Sbuf = (float*)alloc((size_t)Bb * Nn * ODIM * 4);                        // 16.8 MB
    __hip_bfloat16* QA = (__hip_bfloat16*)alloc((size_t)NNODES * NF * 2);           // 4 MB quartered
    __hip_bfloat16* QB = (__hip_bfloat16*)alloc((size_t)NNODES * NF * 2);           // 4 MB quartered
    const bool precomp = (ws_size >= off);

    hipLaunchKernelGGL(k_prep, dim3((PREP_TOTAL + 255) / 256), dim3(256), 0, stream,
                       We, W1, W2, W3, Wn, Wf, dis, DAw, DAb,
                       WeT, W1b, W2b, W3b, W1s, W2s, W3s, Wnb, Web, Wfb, DAf);

    hipLaunchKernelGGL(k_embed_all, dim3(precomp ? (256 + Bb * Nn * Mm / 64) : 256), dim3(256), 0, stream,
                       node_fea, Wnb, bn, nfA, edge_fea, Web, be, efb);

    if (precomp) {
        hipLaunchKernelGGL((k_gemm_s<false>), dim3(Bb * Nn / 64), dim3(256), 0, stream,
                           nfA, W1s, b1, Sbuf);
        hipLaunchKernelGGL((k_conv_q<false>), dim3(2048), dim3(256), 0, stream,
                           nfA, efb, eidx, W1b, Sbuf, a1, QA);
        hipLaunchKernelGGL((k_gemm_s<true>), dim3(Bb * Nn / 64), dim3(256), 0, stream,
                           QA, W2s, b2, Sbuf);
        hipLaunchKernelGGL((k_conv_q<true>), dim3(2048), dim3(256), 0, stream,
                           QA, efb, eidx, W2b, Sbuf, a2, QB);
        hipLaunchKernelGGL((k_gemm_s<true>), dim3(Bb * Nn / 64), dim3(256), 0, stream,
                           QB, W3s, b3, Sbuf);
        hipLaunchKernelGGL((k_conv_q<true>), dim3(2048), dim3(256), 0, stream,
                           QB, efb, eidx, W3b, Sbuf, a3, QA);
        hipLaunchKernelGGL((k_final_mfma<true>), dim3(Bb * Nn / 64), dim3(256), 0, stream,
                           QA, Wfb, bf, out, XT);
    } else {
        hipLaunchKernelGGL((k_conv_mfma<false>), dim3(Bb * Nn / 4), dim3(256), 0, stream,
                           nfA, edge_fea, efb, eidx, WeT, be, W1b, W1s, b1, a1, nfB);
        hipLaunchKernelGGL((k_conv_mfma<false>), dim3(Bb * Nn / 4), dim3(256), 0, stream,
                           nfB, edge_fea, efb, eidx, WeT, be, W2b, W2s, b2, a2, nfA);
        hipLaunchKernelGGL((k_conv_mfma<false>), dim3(Bb * Nn / 4), dim3(256), 0, stream,
                           nfA, edge_fea, efb, eidx, WeT, be, W3b, W3s, b3, a3, nfB);
        hipLaunchKernelGGL((k_final_mfma<false>), dim3(Bb * Nn / 64), dim3(256), 0, stream,
                           nfB, Wfb, bf, out, XT);
    }

    hipLaunchKernelGGL(k_node1_mfma, dim3(Bb * 4), dim3(256), 0, stream, DAf, XT, out);
}